// Round 13
// baseline (876.151 us; speedup 1.0000x reference)
//
#include <hip/hip_runtime.h>

#define NE_N 50000
#define NP_N 25000
#define E_N 200000
#define DIM 128
#define LOG2E 1.4426950408889634f

typedef __attribute__((ext_vector_type(8))) short short8;
typedef __attribute__((ext_vector_type(4))) float f32x4;

static __device__ __forceinline__ ushort f2bf(float f) {
  unsigned x = __float_as_uint(f);
  return (ushort)((x + 0x7fffu + ((x >> 16) & 1u)) >> 16);  // RNE
}
static __device__ __forceinline__ float bf2f(ushort u) {
  return __uint_as_float(((unsigned)u) << 16);
}

// ---------------------------------------------------------------------------
// Fused setup: conv_w (12 blk) | vec (6 blk) | hist+rank (3128 blk).
#define SU_CW 12
#define SU_V 6
#define SU_H 3128
__global__ __launch_bounds__(256) void setup_fused(
    const float* __restrict__ W_src, const float* __restrict__ W_dst,
    const float* __restrict__ att_dst, ushort* __restrict__ WbT,
    float* __restrict__ vec, const int* __restrict__ d0,
    const int* __restrict__ d1, const int* __restrict__ d2,
    const int* __restrict__ d3, int* __restrict__ c0, int* __restrict__ c1,
    int* __restrict__ c2, int* __restrict__ c3, ushort* __restrict__ rk0,
    ushort* __restrict__ rk1, ushort* __restrict__ rk2,
    ushort* __restrict__ rk3) {
  int blk = blockIdx.x;
  int tid = threadIdx.x;
  if (blk < SU_CW) {
    const float* src = W_src + (size_t)blk * DIM * DIM;
    ushort* dst = WbT + (size_t)blk * DIM * DIM;
    for (int i = tid; i < DIM * DIM; i += 256) {
      int k = i >> 7, n = i & 127;
      dst[n * DIM + k] = f2bf(src[i]);
    }
  } else if (blk < SU_CW + SU_V) {
    int b = blk - SU_CW;
    int lt = b * 2 + (tid >> 7);
    int i = tid & 127;
    const float* Wd = W_dst + (size_t)lt * DIM * DIM;
    const float* ad = att_dst + lt * DIM;
    float s = 0.f;
#pragma unroll 8
    for (int j = 0; j < DIM; j++) s += Wd[i * DIM + j] * ad[j];
    vec[lt * DIM + i] = s;
  } else {
    int b = blk - SU_CW - SU_V;
    int ty = b / 782;
    int e = (b % 782) * 256 + tid;
    if (e >= E_N) return;
    const int* dst = ty == 0 ? d0 : ty == 1 ? d1 : ty == 2 ? d2 : d3;
    int* cnt = ty == 0 ? c0 : ty == 1 ? c1 : ty == 2 ? c2 : c3;
    ushort* rk = ty == 0 ? rk0 : ty == 1 ? rk1 : ty == 2 ? rk2 : rk3;
    rk[e] = (ushort)atomicAdd(&cnt[dst[e]], 1);
  }
}

// ---------------------------------------------------------------------------
// CSR scan, now 2 dispatches: scanA (block sums) + scanBC (inline partial
// prefix + writeback). r9's 1-dispatch scan: 92us. r11 coop mega: 1519us.
__global__ __launch_bounds__(256) void scanA_k(
    const int* __restrict__ c0, const int* __restrict__ c1,
    const int* __restrict__ c2, const int* __restrict__ c3,
    int* __restrict__ part) {
  int ty = blockIdx.y;
  const int* cnt = ty == 0 ? c0 : ty == 1 ? c1 : ty == 2 ? c2 : c3;
  int n = (ty == 0 || ty == 3) ? NE_N : NP_N;
  int nblk = (n + 1023) >> 10;
  if ((int)blockIdx.x >= nblk) return;
  int base = blockIdx.x * 1024 + threadIdx.x * 4;
  int s = 0;
#pragma unroll
  for (int j = 0; j < 4; j++) s += (base + j < n) ? cnt[base + j] : 0;
  int lane = threadIdx.x & 63, wid = threadIdx.x >> 6;
#pragma unroll
  for (int off = 32; off > 0; off >>= 1) s += __shfl_xor(s, off, 64);
  __shared__ int ws4[4];
  if (lane == 0) ws4[wid] = s;
  __syncthreads();
  if (threadIdx.x == 0)
    part[ty * 64 + blockIdx.x] = ws4[0] + ws4[1] + ws4[2] + ws4[3];
}

// scanBC: wave 0 re-scans the <=49 partials to get this block's exclusive
// base (49 ints, L2-hot — cheaper than a separate dispatch boundary), then
// the whole block writes its 1024-entry rp range.
__global__ __launch_bounds__(256) void scanBC_k(
    const int* __restrict__ c0, const int* __restrict__ c1,
    const int* __restrict__ c2, const int* __restrict__ c3,
    int* __restrict__ r0, int* __restrict__ r1, int* __restrict__ r2,
    int* __restrict__ r3, const int* __restrict__ part) {
  int ty = blockIdx.y;
  int bx = blockIdx.x;
  const int* cnt = ty == 0 ? c0 : ty == 1 ? c1 : ty == 2 ? c2 : c3;
  int* rp = ty == 0 ? r0 : ty == 1 ? r1 : ty == 2 ? r2 : r3;
  int n = (ty == 0 || ty == 3) ? NE_N : NP_N;
  int nblk = (n + 1023) >> 10;
  if (bx >= nblk) return;

  __shared__ int s_excl;
  if (threadIdx.x < 64) {
    int pl = threadIdx.x;
    int v = (pl < nblk) ? part[ty * 64 + pl] : 0;
    int sc = v;
#pragma unroll
    for (int off = 1; off < 64; off <<= 1) {
      int t = __shfl_up(sc, off, 64);
      if (pl >= off) sc += t;
    }
    if (pl == bx) s_excl = sc - v;
  }
  if (bx == 0 && threadIdx.x == 0) rp[n] = E_N;  // total is always E_N
  __syncthreads();

  int base = bx * 1024 + threadIdx.x * 4;
  int v[4];
#pragma unroll
  for (int j = 0; j < 4; j++) v[j] = (base + j < n) ? cnt[base + j] : 0;
  int s = v[0] + v[1] + v[2] + v[3];
  int lane = threadIdx.x & 63, wid = threadIdx.x >> 6;
  int sc = s;
#pragma unroll
  for (int off = 1; off < 64; off <<= 1) {
    int t = __shfl_up(sc, off, 64);
    if (lane >= off) sc += t;
  }
  __shared__ int ws4[4];
  if (lane == 63) ws4[wid] = sc;
  __syncthreads();
  int wbase = 0;
  for (int w = 0; w < wid; w++) wbase += ws4[w];
  int p = s_excl + wbase + sc - s;
#pragma unroll
  for (int j = 0; j < 4; j++) {
    if (base + j < n) rp[base + j] = p;
    p += v[j];
  }
}

// ---------------------------------------------------------------------------
// GEMM body: operand-swapped MFMA; es (scaled LOG2E) + ed for both dst
// halves. FP32 template: layer 0 reads raw fp32 features (no conv pass).
#define EBLK ((NE_N + 63) / 64)
#define PBLK ((NP_N + 63) / 64)
#define GEMM_BLK (EBLK + PBLK)
template <bool FP32>
static __device__ __forceinline__ void gemm_body(
    int blk, const void* __restrict__ xev, const void* __restrict__ xpv,
    const ushort* __restrict__ WbT, const float* __restrict__ att,
    const float* __restrict__ vec, int l, unsigned char* __restrict__ hsE0,
    unsigned char* __restrict__ hsE1, unsigned char* __restrict__ hsP3,
    unsigned char* __restrict__ hsP2, float* __restrict__ esE0,
    float* __restrict__ esE1, float* __restrict__ esP3,
    float* __restrict__ esP2, float* __restrict__ edEA,
    float* __restrict__ edEB, float* __restrict__ edPA,
    float* __restrict__ edPB) {
  const void* xb;
  const ushort *W0T, *W1T;
  const float *a0, *a1, *dv0, *dv1;
  unsigned char *hs0, *hs1;
  float *es0, *es1, *edA, *edB;
  int N;
  if (blk < EBLK) {
    xb = xev; N = NE_N;
    W0T = WbT + (size_t)(l * 4 + 0) * DIM * DIM;
    W1T = WbT + (size_t)(l * 4 + 1) * DIM * DIM;
    a0 = att + (l * 4 + 0) * DIM; a1 = att + (l * 4 + 1) * DIM;
    dv0 = vec + (l * 4 + 0) * DIM; dv1 = vec + (l * 4 + 3) * DIM;
    hs0 = hsE0; hs1 = hsE1; es0 = esE0; es1 = esE1;
    edA = edEA; edB = edEB;
  } else {
    blk -= EBLK; xb = xpv; N = NP_N;
    W0T = WbT + (size_t)(l * 4 + 3) * DIM * DIM;
    W1T = WbT + (size_t)(l * 4 + 2) * DIM * DIM;
    a0 = att + (l * 4 + 3) * DIM; a1 = att + (l * 4 + 2) * DIM;
    dv0 = vec + (l * 4 + 1) * DIM; dv1 = vec + (l * 4 + 2) * DIM;
    hs0 = hsP3; hs1 = hsP2; es0 = esP3; es1 = esP2;
    edA = edPA; edB = edPB;
  }

  const int wave = threadIdx.x >> 6;
  const int lane = threadIdx.x & 63;
  const int m = lane & 15, quad = lane >> 4;
  const int row0 = blk * 64 + wave * 16;
  if (row0 >= N) return;
  int rowA = row0 + m;
  if (rowA >= N) rowA = N - 1;  // clamp loads; stores guarded

  f32x4 acc0[8], acc1[8];
#pragma unroll
  for (int f = 0; f < 8; f++) {
    acc0[f] = (f32x4){0.f, 0.f, 0.f, 0.f};
    acc1[f] = (f32x4){0.f, 0.f, 0.f, 0.f};
  }

  float edp0 = 0.f, edp1 = 0.f;
  const float* xf32 = (const float*)xb + (size_t)rowA * DIM + quad * 8;
  const ushort* xb16 = (const ushort*)xb + (size_t)rowA * DIM + quad * 8;
#pragma unroll
  for (int k0 = 0; k0 < 4; k0++) {
    short8 xv;
    float xf[8];
    if (FP32) {
      float4 f0 = *(const float4*)(xf32 + k0 * 32);
      float4 f1 = *(const float4*)(xf32 + k0 * 32 + 4);
      xf[0] = f0.x; xf[1] = f0.y; xf[2] = f0.z; xf[3] = f0.w;
      xf[4] = f1.x; xf[5] = f1.y; xf[6] = f1.z; xf[7] = f1.w;
#pragma unroll
      for (int j = 0; j < 8; j++) xv[j] = (short)f2bf(xf[j]);
    } else {
      xv = *(const short8*)(xb16 + k0 * 32);
#pragma unroll
      for (int j = 0; j < 8; j++) xf[j] = bf2f((ushort)xv[j]);
    }
    // ed partials
    {
      int off = k0 * 32 + quad * 8;
      float4 vA0 = *(const float4*)&dv0[off];
      float4 vA1 = *(const float4*)&dv0[off + 4];
      float4 vB0 = *(const float4*)&dv1[off];
      float4 vB1 = *(const float4*)&dv1[off + 4];
      edp0 += xf[0] * vA0.x + xf[1] * vA0.y + xf[2] * vA0.z + xf[3] * vA0.w +
              xf[4] * vA1.x + xf[5] * vA1.y + xf[6] * vA1.z + xf[7] * vA1.w;
      edp1 += xf[0] * vB0.x + xf[1] * vB0.y + xf[2] * vB0.z + xf[3] * vB0.w +
              xf[4] * vB1.x + xf[5] * vB1.y + xf[6] * vB1.z + xf[7] * vB1.w;
    }
#pragma unroll
    for (int f = 0; f < 8; f++) {
      size_t boff = (size_t)(f * 16 + m) * DIM + k0 * 32 + quad * 8;
      short8 w0 = *(const short8*)(W0T + boff);
      acc0[f] = __builtin_amdgcn_mfma_f32_16x16x32_bf16(w0, xv, acc0[f], 0, 0, 0);
      short8 w1 = *(const short8*)(W1T + boff);
      acc1[f] = __builtin_amdgcn_mfma_f32_16x16x32_bf16(w1, xv, acc1[f], 0, 0, 0);
    }
  }

  const int row = row0 + m;
  edp0 += __shfl_xor(edp0, 16, 64);
  edp0 += __shfl_xor(edp0, 32, 64);
  edp1 += __shfl_xor(edp1, 16, 64);
  edp1 += __shfl_xor(edp1, 32, 64);
  if (quad == 0 && row < N) {
    edA[row] = edp0 * LOG2E;
    edB[row] = edp1 * LOG2E;
  }

#pragma unroll
  for (int set = 0; set < 2; set++) {
    f32x4* acc = set ? acc1 : acc0;
    const float* as = set ? a1 : a0;
    float* es = set ? es1 : es0;
    unsigned char* hs = set ? hs1 : hs0;

    float esum = 0.f;
#pragma unroll
    for (int f = 0; f < 8; f++) {
      float4 av = *(const float4*)&as[f * 16 + quad * 4];
      esum += acc[f][0] * av.x + acc[f][1] * av.y + acc[f][2] * av.z +
              acc[f][3] * av.w;
    }
    esum += __shfl_xor(esum, 16, 64);
    esum += __shfl_xor(esum, 32, 64);
    if (quad == 0 && row < N) es[row] = esum * LOG2E;

    if (row < N) {
#pragma unroll
      for (int f = 0; f < 8; f++) {
        int w = __builtin_amdgcn_cvt_pk_fp8_f32(acc[f][0], acc[f][1], 0, false);
        w = __builtin_amdgcn_cvt_pk_fp8_f32(acc[f][2], acc[f][3], w, true);
        *(unsigned*)&hs[(size_t)row * DIM + f * 16 + quad * 4] = (unsigned)w;
      }
    }
  }
}

// standalone gemm (layers 1,2 — bf16 input)
__global__ __launch_bounds__(256) void gemm_k(
    const ushort* __restrict__ xe, const ushort* __restrict__ xp,
    const ushort* __restrict__ WbT, const float* __restrict__ att,
    const float* __restrict__ vec, int l, unsigned char* __restrict__ hsE0,
    unsigned char* __restrict__ hsE1, unsigned char* __restrict__ hsP3,
    unsigned char* __restrict__ hsP2, float* __restrict__ esE0,
    float* __restrict__ esE1, float* __restrict__ esP3,
    float* __restrict__ esP2, float* __restrict__ edEA,
    float* __restrict__ edEB, float* __restrict__ edPA,
    float* __restrict__ edPB) {
  gemm_body<false>(blockIdx.x, xe, xp, WbT, att, vec, l, hsE0, hsE1, hsP3,
                   hsP2, esE0, esE1, esP3, esP2, edEA, edEB, edPA, edPB);
}

// fused atomic-free CSR-fill + layer-0 gemm (fp32 input)
__global__ __launch_bounds__(256) void fill_gemm0_k(
    const float* __restrict__ xe, const float* __restrict__ xp,
    const ushort* __restrict__ WbT, const float* __restrict__ att,
    const float* __restrict__ vec, unsigned char* __restrict__ hsE0,
    unsigned char* __restrict__ hsE1, unsigned char* __restrict__ hsP3,
    unsigned char* __restrict__ hsP2, float* __restrict__ esE0,
    float* __restrict__ esE1, float* __restrict__ esP3,
    float* __restrict__ esP2, float* __restrict__ edEA,
    float* __restrict__ edEB, float* __restrict__ edPA,
    float* __restrict__ edPB, const int* __restrict__ s0,
    const int* __restrict__ s1, const int* __restrict__ s2,
    const int* __restrict__ s3, const int* __restrict__ d0,
    const int* __restrict__ d1, const int* __restrict__ d2,
    const int* __restrict__ d3, const ushort* __restrict__ rk0,
    const ushort* __restrict__ rk1, const ushort* __restrict__ rk2,
    const ushort* __restrict__ rk3, const int* __restrict__ r0,
    const int* __restrict__ r1, const int* __restrict__ r2,
    const int* __restrict__ r3, ushort* __restrict__ o0,
    ushort* __restrict__ o1, ushort* __restrict__ o2,
    ushort* __restrict__ o3) {
  int blk = blockIdx.x;
  if (blk < GEMM_BLK) {
    gemm_body<true>(blk, xe, xp, WbT, att, vec, 0, hsE0, hsE1, hsP3, hsP2,
                    esE0, esE1, esP3, esP2, edEA, edEB, edPA, edPB);
  } else {
    int b = blk - GEMM_BLK;
    int ty = b / 782;
    int e = (b % 782) * 256 + threadIdx.x;
    if (e >= E_N) return;
    const int* src = ty == 0 ? s0 : ty == 1 ? s1 : ty == 2 ? s2 : s3;
    const int* dst = ty == 0 ? d0 : ty == 1 ? d1 : ty == 2 ? d2 : d3;
    const ushort* rk = ty == 0 ? rk0 : ty == 1 ? rk1 : ty == 2 ? rk2 : rk3;
    const int* rp = ty == 0 ? r0 : ty == 1 ? r1 : ty == 2 ? r2 : r3;
    ushort* out = ty == 0 ? o0 : ty == 1 ? o1 : ty == 2 ? o2 : o3;
    out[rp[dst[e]] + rk[e]] = (ushort)src[e];
  }
}

// ---------------------------------------------------------------------------
// Combined dual-type gather; the two type-halves run concurrently (slots 0-3
// walk half A, 4-7 walk half B). to_csum=0: write bf16 feature rows (+bias).
// to_csum=1 (last layer): rows are consumed only by the column-sum, so skip
// the row write entirely and accumulate into csum via LDS + global atomics;
// bias is added analytically in final_proj.
__global__ __launch_bounds__(256) void gat_gather_all(
    const int* __restrict__ rp0, const ushort* __restrict__ ss0,
    const int* __restrict__ rp1, const ushort* __restrict__ ss1,
    const int* __restrict__ rp2, const ushort* __restrict__ ss2,
    const int* __restrict__ rp3, const ushort* __restrict__ ss3,
    const float* __restrict__ esE0, const unsigned char* __restrict__ hsE0,
    const float* __restrict__ esE1, const unsigned char* __restrict__ hsE1,
    const float* __restrict__ esP3, const unsigned char* __restrict__ hsP3,
    const float* __restrict__ esP2, const unsigned char* __restrict__ hsP2,
    const float* __restrict__ edEA, const float* __restrict__ edEB,
    const float* __restrict__ edPA, const float* __restrict__ edPB,
    const float* __restrict__ bias, int l, ushort* __restrict__ outxe,
    ushort* __restrict__ outxp, int to_csum, float* __restrict__ csum) {
  const int wid = (blockIdx.x * 256 + threadIdx.x) >> 6;
  const int lane = threadIdx.x & 63;
  const int slot = lane >> 3, sub = lane & 7;
  const int half = slot >> 2;   // 0: type-half A, 1: type-half B
  const int hslot = slot & 3;   // slot within the half
  const bool active = wid < NE_N + NP_N;

  float v0 = 0.f, v1 = 0.f;
  const float *b0 = bias, *b1 = bias;
  ushort* outb = outxe;
  int node = 0;

  if (active) {
    const int *rpA, *rpB;
    const ushort *ssA, *ssB;
    const float *esA, *esB;
    const unsigned char *hsA, *hsB;
    const float *edA, *edB;
    if (wid < NE_N) {  // e-dst: ee (A) + pe (B)
      node = wid;
      rpA = rp0; ssA = ss0; esA = esE0; hsA = hsE0;
      rpB = rp3; ssB = ss3; esB = esP3; hsB = hsP3;
      edA = edEA; edB = edEB;
      b0 = bias + (l * 4 + 0) * DIM; b1 = bias + (l * 4 + 3) * DIM;
      outb = outxe;
    } else {  // p-dst: ep (A) + pp (B)
      node = wid - NE_N;
      rpA = rp1; ssA = ss1; esA = esE1; hsA = hsE1;
      rpB = rp2; ssB = ss2; esB = esP2; hsB = hsP2;
      edA = edPA; edB = edPB;
      b0 = bias + (l * 4 + 1) * DIM; b1 = bias + (l * 4 + 2) * DIM;
      outb = outxp;
    }

    const int* rp = half ? rpB : rpA;
    const ushort* ss = half ? ssB : ssA;
    const float* es = half ? esB : esA;
    const unsigned char* hs = half ? hsB : hsA;
    const float edv = half ? edB[node] : edA[node];
    const int beg = rp[node], end = rp[node + 1];

    float acc[16];
#pragma unroll
    for (int j = 0; j < 16; j++) acc[j] = 0.f;
    float sw = 0.f;

    for (int e = beg + hslot; e < end; e += 4) {
      int s = ss[e];
      float w = exp2f(fmaxf(es[s] + edv, 0.f));
      sw += w;
      uint4 h = *(const uint4*)&hs[(size_t)s * DIM + sub * 16];
      auto p0 = __builtin_amdgcn_cvt_pk_f32_fp8((int)h.x, false);
      auto p1 = __builtin_amdgcn_cvt_pk_f32_fp8((int)h.x, true);
      auto p2 = __builtin_amdgcn_cvt_pk_f32_fp8((int)h.y, false);
      auto p3 = __builtin_amdgcn_cvt_pk_f32_fp8((int)h.y, true);
      auto p4 = __builtin_amdgcn_cvt_pk_f32_fp8((int)h.z, false);
      auto p5 = __builtin_amdgcn_cvt_pk_f32_fp8((int)h.z, true);
      auto p6 = __builtin_amdgcn_cvt_pk_f32_fp8((int)h.w, false);
      auto p7 = __builtin_amdgcn_cvt_pk_f32_fp8((int)h.w, true);
      acc[0] += w * p0[0];  acc[1] += w * p0[1];
      acc[2] += w * p1[0];  acc[3] += w * p1[1];
      acc[4] += w * p2[0];  acc[5] += w * p2[1];
      acc[6] += w * p3[0];  acc[7] += w * p3[1];
      acc[8] += w * p4[0];  acc[9] += w * p4[1];
      acc[10] += w * p5[0]; acc[11] += w * p5[1];
      acc[12] += w * p6[0]; acc[13] += w * p6[1];
      acc[14] += w * p7[0]; acc[15] += w * p7[1];
    }

    // sw over the 4 slots of THIS half (lane bits 3,4)
    sw += __shfl_xor(sw, 8, 64);
    sw += __shfl_xor(sw, 16, 64);
    const float inv = 1.f / fmaxf(sw, 1e-16f);

    float res[16];
#pragma unroll
    for (int j = 0; j < 16; j++) res[j] = acc[j] * inv;

    // combine: slot-partials within half (xor 8,16) + across halves (xor 32)
#pragma unroll
    for (int j = 0; j < 16; j++) {
      res[j] += __shfl_xor(res[j], 8, 64);
      res[j] += __shfl_xor(res[j], 16, 64);
      res[j] += __shfl_xor(res[j], 32, 64);
    }
    v0 = res[slot * 2];
    v1 = res[slot * 2 + 1];
  }

  const int d = sub * 16 + slot * 2;
  if (to_csum) {
    __shared__ float lsum[128];
    if (threadIdx.x < 128) lsum[threadIdx.x] = 0.f;
    __syncthreads();
    if (active) {
      atomicAdd(&lsum[d], v0);
      atomicAdd(&lsum[d + 1], v1);
    }
    __syncthreads();
    if (threadIdx.x < 128)
      unsafeAtomicAdd(&csum[threadIdx.x], lsum[threadIdx.x]);
  } else if (active) {
    float2 bb0 = *(const float2*)&b0[d];
    float2 bb1 = *(const float2*)&b1[d];
    ushort2 o;
    o.x = f2bf(v0 + bb0.x + bb1.x);
    o.y = f2bf(v1 + bb0.y + bb1.y);
    *(ushort2*)&outb[(size_t)node * DIM + d] = o;
  }
}

// ---------------------------------------------------------------------------
// final: out[j] = (csum + NE*(bE0+bE1) + NP*(bP0+bP1)) @ lin_W / N + lin_b
__global__ void final_proj(const float* __restrict__ csum,
                           const float* __restrict__ bias,
                           const float* __restrict__ lin_W,
                           const float* __restrict__ lin_b,
                           float* __restrict__ out) {
  int j = threadIdx.x;
  if (j >= 2) return;
  const float* bE0 = bias + (2 * 4 + 0) * DIM;
  const float* bE1 = bias + (2 * 4 + 3) * DIM;
  const float* bP0 = bias + (2 * 4 + 1) * DIM;
  const float* bP1 = bias + (2 * 4 + 2) * DIM;
  float s = 0.f;
#pragma unroll 8
  for (int k = 0; k < DIM; k++) {
    float col = csum[k] + (float)NE_N * (bE0[k] + bE1[k]) +
                (float)NP_N * (bP0[k] + bP1[k]);
    s += col * lin_W[k * 2 + j];
  }
  out[j] = s / (float)(NE_N + NP_N) + lin_b[j];
}

// ---------------------------------------------------------------------------
extern "C" void kernel_launch(void* const* d_in, const int* in_sizes, int n_in,
                              void* d_out, int out_size, void* d_ws,
                              size_t ws_size, hipStream_t stream) {
  const float* x_elem  = (const float*)d_in[0];
  const float* x_proc  = (const float*)d_in[1];
  const float* W_src   = (const float*)d_in[2];
  const float* W_dst   = (const float*)d_in[3];
  const float* att_src = (const float*)d_in[4];
  const float* att_dst = (const float*)d_in[5];
  const float* bias    = (const float*)d_in[6];
  const float* lin_W   = (const float*)d_in[7];
  const float* lin_b   = (const float*)d_in[8];
  const int* esrc[4] = {(const int*)d_in[9],  (const int*)d_in[11],
                        (const int*)d_in[13], (const int*)d_in[15]};
  const int* edst[4] = {(const int*)d_in[10], (const int*)d_in[12],
                        (const int*)d_in[14], (const int*)d_in[16]};

  // ---- workspace carve-up (16B-aligned chunks) ----
  char* p = (char*)d_ws;
  ushort* xe_bf[2]; ushort* xp_bf[2];
  xe_bf[0] = (ushort*)p; p += (size_t)NE_N * DIM * 2;
  xe_bf[1] = (ushort*)p; p += (size_t)NE_N * DIM * 2;
  xp_bf[0] = (ushort*)p; p += (size_t)NP_N * DIM * 2;
  xp_bf[1] = (ushort*)p; p += (size_t)NP_N * DIM * 2;
  unsigned char* hsE0 = (unsigned char*)p; p += (size_t)NE_N * DIM;  // W[l,0]
  unsigned char* hsE1 = (unsigned char*)p; p += (size_t)NE_N * DIM;  // W[l,1]
  unsigned char* hsP3 = (unsigned char*)p; p += (size_t)NP_N * DIM;  // W[l,3]
  unsigned char* hsP2 = (unsigned char*)p; p += (size_t)NP_N * DIM;  // W[l,2]
  ushort* WbT = (ushort*)p; p += (size_t)12 * DIM * DIM * 2;
  float* esE0 = (float*)p; p += (size_t)NE_N * 4;
  float* esE1 = (float*)p; p += (size_t)NE_N * 4;
  float* esP3 = (float*)p; p += (size_t)NP_N * 4;
  float* esP2 = (float*)p; p += (size_t)NP_N * 4;
  float* edEA = (float*)p; p += (size_t)NE_N * 4;
  float* edEB = (float*)p; p += (size_t)NE_N * 4;
  float* edPA = (float*)p; p += (size_t)NP_N * 4;
  float* edPB = (float*)p; p += (size_t)NP_N * 4;
  float* vec = (float*)p; p += 12 * DIM * 4;
  int* parti = (int*)p; p += 4 * 64 * 4;
  // cnt[4] + csum contiguous -> single memset
  int* cnt[4];
  for (int t = 0; t < 4; t++) { cnt[t] = (int*)p; p += (NE_N + 4) * 4; }
  float* csum = (float*)p; p += DIM * 4;
  int* rp[4];
  for (int t = 0; t < 4; t++) { rp[t] = (int*)p; p += (NE_N + 4) * 4; }
  ushort* ssrc[4];
  for (int t = 0; t < 4; t++) { ssrc[t] = (ushort*)p; p += (size_t)E_N * 2; }
  ushort* rank[4];
  for (int t = 0; t < 4; t++) { rank[t] = (ushort*)p; p += (size_t)E_N * 2; }

  // ---- zero cnts + csum in one memset ----
  hipMemsetAsync(cnt[0], 0, 4 * (NE_N + 4) * sizeof(int) + DIM * sizeof(float),
                 stream);

  // ---- fused setup: conv_w | vec | hist+rank ----
  setup_fused<<<SU_CW + SU_V + SU_H, 256, 0, stream>>>(
      W_src, W_dst, att_dst, WbT, vec, edst[0], edst[1], edst[2], edst[3],
      cnt[0], cnt[1], cnt[2], cnt[3], rank[0], rank[1], rank[2], rank[3]);

  // ---- 2-dispatch hierarchical CSR scan ----
  scanA_k<<<dim3(49, 4), 256, 0, stream>>>(cnt[0], cnt[1], cnt[2], cnt[3],
                                           parti);
  scanBC_k<<<dim3(49, 4), 256, 0, stream>>>(cnt[0], cnt[1], cnt[2], cnt[3],
                                            rp[0], rp[1], rp[2], rp[3], parti);

  // ---- atomic-free fill + layer-0 gemm (fp32 input) fused ----
  fill_gemm0_k<<<GEMM_BLK + 3128, 256, 0, stream>>>(
      x_elem, x_proc, WbT, att_src, vec, hsE0, hsE1, hsP3, hsP2, esE0, esE1,
      esP3, esP2, edEA, edEB, edPA, edPB, esrc[0], esrc[1], esrc[2], esrc[3],
      edst[0], edst[1], edst[2], edst[3], rank[0], rank[1], rank[2], rank[3],
      rp[0], rp[1], rp[2], rp[3], ssrc[0], ssrc[1], ssrc[2], ssrc[3]);

  // ---- layers ----
  int c = 0;
  for (int l = 0; l < 3; l++) {
    if (l > 0) {
      gemm_k<<<GEMM_BLK, 256, 0, stream>>>(
          xe_bf[c], xp_bf[c], WbT, att_src, vec, l, hsE0, hsE1, hsP3, hsP2,
          esE0, esE1, esP3, esP2, edEA, edEB, edPA, edPB);
    }
    int to_csum = (l == 2) ? 1 : 0;
    gat_gather_all<<<(NE_N + NP_N) / 4, 256, 0, stream>>>(
        rp[0], ssrc[0], rp[1], ssrc[1], rp[2], ssrc[2], rp[3], ssrc[3], esE0,
        hsE0, esE1, hsE1, esP3, hsP3, esP2, hsP2, edEA, edEB, edPA, edPB,
        bias, l, xe_bf[1 - c], xp_bf[1 - c], to_csum, csum);
    c = 1 - c;
  }

  final_proj<<<1, 64, 0, stream>>>(csum, bias, lin_W, lin_b, (float*)d_out);
}

// Round 14
// 508.011 us; speedup vs baseline: 1.7247x; 1.7247x over previous
//
#include <hip/hip_runtime.h>

#define NE_N 50000
#define NP_N 25000
#define E_N 200000
#define DIM 128
#define LOG2E 1.4426950408889634f
#define NREP 64  // csum replicas: spreads 2.4M atomics over 64x the lines

typedef __attribute__((ext_vector_type(8))) short short8;
typedef __attribute__((ext_vector_type(4))) float f32x4;

static __device__ __forceinline__ ushort f2bf(float f) {
  unsigned x = __float_as_uint(f);
  return (ushort)((x + 0x7fffu + ((x >> 16) & 1u)) >> 16);  // RNE
}
static __device__ __forceinline__ float bf2f(ushort u) {
  return __uint_as_float(((unsigned)u) << 16);
}

// ---------------------------------------------------------------------------
// Fused setup: conv_w (12 blk) | vec (6 blk) | hist+rank (3128 blk).
#define SU_CW 12
#define SU_V 6
#define SU_H 3128
__global__ __launch_bounds__(256) void setup_fused(
    const float* __restrict__ W_src, const float* __restrict__ W_dst,
    const float* __restrict__ att_dst, ushort* __restrict__ WbT,
    float* __restrict__ vec, const int* __restrict__ d0,
    const int* __restrict__ d1, const int* __restrict__ d2,
    const int* __restrict__ d3, int* __restrict__ c0, int* __restrict__ c1,
    int* __restrict__ c2, int* __restrict__ c3, ushort* __restrict__ rk0,
    ushort* __restrict__ rk1, ushort* __restrict__ rk2,
    ushort* __restrict__ rk3) {
  int blk = blockIdx.x;
  int tid = threadIdx.x;
  if (blk < SU_CW) {
    const float* src = W_src + (size_t)blk * DIM * DIM;
    ushort* dst = WbT + (size_t)blk * DIM * DIM;
    for (int i = tid; i < DIM * DIM; i += 256) {
      int k = i >> 7, n = i & 127;
      dst[n * DIM + k] = f2bf(src[i]);
    }
  } else if (blk < SU_CW + SU_V) {
    int b = blk - SU_CW;
    int lt = b * 2 + (tid >> 7);
    int i = tid & 127;
    const float* Wd = W_dst + (size_t)lt * DIM * DIM;
    const float* ad = att_dst + lt * DIM;
    float s = 0.f;
#pragma unroll 8
    for (int j = 0; j < DIM; j++) s += Wd[i * DIM + j] * ad[j];
    vec[lt * DIM + i] = s;
  } else {
    int b = blk - SU_CW - SU_V;
    int ty = b / 782;
    int e = (b % 782) * 256 + tid;
    if (e >= E_N) return;
    const int* dst = ty == 0 ? d0 : ty == 1 ? d1 : ty == 2 ? d2 : d3;
    int* cnt = ty == 0 ? c0 : ty == 1 ? c1 : ty == 2 ? c2 : c3;
    ushort* rk = ty == 0 ? rk0 : ty == 1 ? rk1 : ty == 2 ? rk2 : rk3;
    rk[e] = (ushort)atomicAdd(&cnt[dst[e]], 1);
  }
}

// ---------------------------------------------------------------------------
// CSR scan, 2 dispatches: scanA (block sums) + scanBC (inline partial prefix
// + writeback). r9's 1-dispatch scan: 92us. r11 coop mega: 1519us.
__global__ __launch_bounds__(256) void scanA_k(
    const int* __restrict__ c0, const int* __restrict__ c1,
    const int* __restrict__ c2, const int* __restrict__ c3,
    int* __restrict__ part) {
  int ty = blockIdx.y;
  const int* cnt = ty == 0 ? c0 : ty == 1 ? c1 : ty == 2 ? c2 : c3;
  int n = (ty == 0 || ty == 3) ? NE_N : NP_N;
  int nblk = (n + 1023) >> 10;
  if ((int)blockIdx.x >= nblk) return;
  int base = blockIdx.x * 1024 + threadIdx.x * 4;
  int s = 0;
#pragma unroll
  for (int j = 0; j < 4; j++) s += (base + j < n) ? cnt[base + j] : 0;
  int lane = threadIdx.x & 63, wid = threadIdx.x >> 6;
#pragma unroll
  for (int off = 32; off > 0; off >>= 1) s += __shfl_xor(s, off, 64);
  __shared__ int ws4[4];
  if (lane == 0) ws4[wid] = s;
  __syncthreads();
  if (threadIdx.x == 0)
    part[ty * 64 + blockIdx.x] = ws4[0] + ws4[1] + ws4[2] + ws4[3];
}

__global__ __launch_bounds__(256) void scanBC_k(
    const int* __restrict__ c0, const int* __restrict__ c1,
    const int* __restrict__ c2, const int* __restrict__ c3,
    int* __restrict__ r0, int* __restrict__ r1, int* __restrict__ r2,
    int* __restrict__ r3, const int* __restrict__ part) {
  int ty = blockIdx.y;
  int bx = blockIdx.x;
  const int* cnt = ty == 0 ? c0 : ty == 1 ? c1 : ty == 2 ? c2 : c3;
  int* rp = ty == 0 ? r0 : ty == 1 ? r1 : ty == 2 ? r2 : r3;
  int n = (ty == 0 || ty == 3) ? NE_N : NP_N;
  int nblk = (n + 1023) >> 10;
  if (bx >= nblk) return;

  __shared__ int s_excl;
  if (threadIdx.x < 64) {
    int pl = threadIdx.x;
    int v = (pl < nblk) ? part[ty * 64 + pl] : 0;
    int sc = v;
#pragma unroll
    for (int off = 1; off < 64; off <<= 1) {
      int t = __shfl_up(sc, off, 64);
      if (pl >= off) sc += t;
    }
    if (pl == bx) s_excl = sc - v;
  }
  if (bx == 0 && threadIdx.x == 0) rp[n] = E_N;  // total is always E_N
  __syncthreads();

  int base = bx * 1024 + threadIdx.x * 4;
  int v[4];
#pragma unroll
  for (int j = 0; j < 4; j++) v[j] = (base + j < n) ? cnt[base + j] : 0;
  int s = v[0] + v[1] + v[2] + v[3];
  int lane = threadIdx.x & 63, wid = threadIdx.x >> 6;
  int sc = s;
#pragma unroll
  for (int off = 1; off < 64; off <<= 1) {
    int t = __shfl_up(sc, off, 64);
    if (lane >= off) sc += t;
  }
  __shared__ int ws4[4];
  if (lane == 63) ws4[wid] = sc;
  __syncthreads();
  int wbase = 0;
  for (int w = 0; w < wid; w++) wbase += ws4[w];
  int p = s_excl + wbase + sc - s;
#pragma unroll
  for (int j = 0; j < 4; j++) {
    if (base + j < n) rp[base + j] = p;
    p += v[j];
  }
}

// ---------------------------------------------------------------------------
// GEMM body: operand-swapped MFMA; es (scaled LOG2E) + ed for both dst
// halves. FP32 template: layer 0 reads raw fp32 features (no conv pass).
#define EBLK ((NE_N + 63) / 64)
#define PBLK ((NP_N + 63) / 64)
#define GEMM_BLK (EBLK + PBLK)
template <bool FP32>
static __device__ __forceinline__ void gemm_body(
    int blk, const void* __restrict__ xev, const void* __restrict__ xpv,
    const ushort* __restrict__ WbT, const float* __restrict__ att,
    const float* __restrict__ vec, int l, unsigned char* __restrict__ hsE0,
    unsigned char* __restrict__ hsE1, unsigned char* __restrict__ hsP3,
    unsigned char* __restrict__ hsP2, float* __restrict__ esE0,
    float* __restrict__ esE1, float* __restrict__ esP3,
    float* __restrict__ esP2, float* __restrict__ edEA,
    float* __restrict__ edEB, float* __restrict__ edPA,
    float* __restrict__ edPB) {
  const void* xb;
  const ushort *W0T, *W1T;
  const float *a0, *a1, *dv0, *dv1;
  unsigned char *hs0, *hs1;
  float *es0, *es1, *edA, *edB;
  int N;
  if (blk < EBLK) {
    xb = xev; N = NE_N;
    W0T = WbT + (size_t)(l * 4 + 0) * DIM * DIM;
    W1T = WbT + (size_t)(l * 4 + 1) * DIM * DIM;
    a0 = att + (l * 4 + 0) * DIM; a1 = att + (l * 4 + 1) * DIM;
    dv0 = vec + (l * 4 + 0) * DIM; dv1 = vec + (l * 4 + 3) * DIM;
    hs0 = hsE0; hs1 = hsE1; es0 = esE0; es1 = esE1;
    edA = edEA; edB = edEB;
  } else {
    blk -= EBLK; xb = xpv; N = NP_N;
    W0T = WbT + (size_t)(l * 4 + 3) * DIM * DIM;
    W1T = WbT + (size_t)(l * 4 + 2) * DIM * DIM;
    a0 = att + (l * 4 + 3) * DIM; a1 = att + (l * 4 + 2) * DIM;
    dv0 = vec + (l * 4 + 1) * DIM; dv1 = vec + (l * 4 + 2) * DIM;
    hs0 = hsP3; hs1 = hsP2; es0 = esP3; es1 = esP2;
    edA = edPA; edB = edPB;
  }

  const int wave = threadIdx.x >> 6;
  const int lane = threadIdx.x & 63;
  const int m = lane & 15, quad = lane >> 4;
  const int row0 = blk * 64 + wave * 16;
  if (row0 >= N) return;
  int rowA = row0 + m;
  if (rowA >= N) rowA = N - 1;  // clamp loads; stores guarded

  f32x4 acc0[8], acc1[8];
#pragma unroll
  for (int f = 0; f < 8; f++) {
    acc0[f] = (f32x4){0.f, 0.f, 0.f, 0.f};
    acc1[f] = (f32x4){0.f, 0.f, 0.f, 0.f};
  }

  float edp0 = 0.f, edp1 = 0.f;
  const float* xf32 = (const float*)xb + (size_t)rowA * DIM + quad * 8;
  const ushort* xb16 = (const ushort*)xb + (size_t)rowA * DIM + quad * 8;
#pragma unroll
  for (int k0 = 0; k0 < 4; k0++) {
    short8 xv;
    float xf[8];
    if (FP32) {
      float4 f0 = *(const float4*)(xf32 + k0 * 32);
      float4 f1 = *(const float4*)(xf32 + k0 * 32 + 4);
      xf[0] = f0.x; xf[1] = f0.y; xf[2] = f0.z; xf[3] = f0.w;
      xf[4] = f1.x; xf[5] = f1.y; xf[6] = f1.z; xf[7] = f1.w;
#pragma unroll
      for (int j = 0; j < 8; j++) xv[j] = (short)f2bf(xf[j]);
    } else {
      xv = *(const short8*)(xb16 + k0 * 32);
#pragma unroll
      for (int j = 0; j < 8; j++) xf[j] = bf2f((ushort)xv[j]);
    }
    // ed partials
    {
      int off = k0 * 32 + quad * 8;
      float4 vA0 = *(const float4*)&dv0[off];
      float4 vA1 = *(const float4*)&dv0[off + 4];
      float4 vB0 = *(const float4*)&dv1[off];
      float4 vB1 = *(const float4*)&dv1[off + 4];
      edp0 += xf[0] * vA0.x + xf[1] * vA0.y + xf[2] * vA0.z + xf[3] * vA0.w +
              xf[4] * vA1.x + xf[5] * vA1.y + xf[6] * vA1.z + xf[7] * vA1.w;
      edp1 += xf[0] * vB0.x + xf[1] * vB0.y + xf[2] * vB0.z + xf[3] * vB0.w +
              xf[4] * vB1.x + xf[5] * vB1.y + xf[6] * vB1.z + xf[7] * vB1.w;
    }
#pragma unroll
    for (int f = 0; f < 8; f++) {
      size_t boff = (size_t)(f * 16 + m) * DIM + k0 * 32 + quad * 8;
      short8 w0 = *(const short8*)(W0T + boff);
      acc0[f] = __builtin_amdgcn_mfma_f32_16x16x32_bf16(w0, xv, acc0[f], 0, 0, 0);
      short8 w1 = *(const short8*)(W1T + boff);
      acc1[f] = __builtin_amdgcn_mfma_f32_16x16x32_bf16(w1, xv, acc1[f], 0, 0, 0);
    }
  }

  const int row = row0 + m;
  edp0 += __shfl_xor(edp0, 16, 64);
  edp0 += __shfl_xor(edp0, 32, 64);
  edp1 += __shfl_xor(edp1, 16, 64);
  edp1 += __shfl_xor(edp1, 32, 64);
  if (quad == 0 && row < N) {
    edA[row] = edp0 * LOG2E;
    edB[row] = edp1 * LOG2E;
  }

#pragma unroll
  for (int set = 0; set < 2; set++) {
    f32x4* acc = set ? acc1 : acc0;
    const float* as = set ? a1 : a0;
    float* es = set ? es1 : es0;
    unsigned char* hs = set ? hs1 : hs0;

    float esum = 0.f;
#pragma unroll
    for (int f = 0; f < 8; f++) {
      float4 av = *(const float4*)&as[f * 16 + quad * 4];
      esum += acc[f][0] * av.x + acc[f][1] * av.y + acc[f][2] * av.z +
              acc[f][3] * av.w;
    }
    esum += __shfl_xor(esum, 16, 64);
    esum += __shfl_xor(esum, 32, 64);
    if (quad == 0 && row < N) es[row] = esum * LOG2E;

    if (row < N) {
#pragma unroll
      for (int f = 0; f < 8; f++) {
        int w = __builtin_amdgcn_cvt_pk_fp8_f32(acc[f][0], acc[f][1], 0, false);
        w = __builtin_amdgcn_cvt_pk_fp8_f32(acc[f][2], acc[f][3], w, true);
        *(unsigned*)&hs[(size_t)row * DIM + f * 16 + quad * 4] = (unsigned)w;
      }
    }
  }
}

// standalone gemm (layers 1,2 — bf16 input)
__global__ __launch_bounds__(256) void gemm_k(
    const ushort* __restrict__ xe, const ushort* __restrict__ xp,
    const ushort* __restrict__ WbT, const float* __restrict__ att,
    const float* __restrict__ vec, int l, unsigned char* __restrict__ hsE0,
    unsigned char* __restrict__ hsE1, unsigned char* __restrict__ hsP3,
    unsigned char* __restrict__ hsP2, float* __restrict__ esE0,
    float* __restrict__ esE1, float* __restrict__ esP3,
    float* __restrict__ esP2, float* __restrict__ edEA,
    float* __restrict__ edEB, float* __restrict__ edPA,
    float* __restrict__ edPB) {
  gemm_body<false>(blockIdx.x, xe, xp, WbT, att, vec, l, hsE0, hsE1, hsP3,
                   hsP2, esE0, esE1, esP3, esP2, edEA, edEB, edPA, edPB);
}

// fused atomic-free CSR-fill + layer-0 gemm (fp32 input)
__global__ __launch_bounds__(256) void fill_gemm0_k(
    const float* __restrict__ xe, const float* __restrict__ xp,
    const ushort* __restrict__ WbT, const float* __restrict__ att,
    const float* __restrict__ vec, unsigned char* __restrict__ hsE0,
    unsigned char* __restrict__ hsE1, unsigned char* __restrict__ hsP3,
    unsigned char* __restrict__ hsP2, float* __restrict__ esE0,
    float* __restrict__ esE1, float* __restrict__ esP3,
    float* __restrict__ esP2, float* __restrict__ edEA,
    float* __restrict__ edEB, float* __restrict__ edPA,
    float* __restrict__ edPB, const int* __restrict__ s0,
    const int* __restrict__ s1, const int* __restrict__ s2,
    const int* __restrict__ s3, const int* __restrict__ d0,
    const int* __restrict__ d1, const int* __restrict__ d2,
    const int* __restrict__ d3, const ushort* __restrict__ rk0,
    const ushort* __restrict__ rk1, const ushort* __restrict__ rk2,
    const ushort* __restrict__ rk3, const int* __restrict__ r0,
    const int* __restrict__ r1, const int* __restrict__ r2,
    const int* __restrict__ r3, ushort* __restrict__ o0,
    ushort* __restrict__ o1, ushort* __restrict__ o2,
    ushort* __restrict__ o3) {
  int blk = blockIdx.x;
  if (blk < GEMM_BLK) {
    gemm_body<true>(blk, xe, xp, WbT, att, vec, 0, hsE0, hsE1, hsP3, hsP2,
                    esE0, esE1, esP3, esP2, edEA, edEB, edPA, edPB);
  } else {
    int b = blk - GEMM_BLK;
    int ty = b / 782;
    int e = (b % 782) * 256 + threadIdx.x;
    if (e >= E_N) return;
    const int* src = ty == 0 ? s0 : ty == 1 ? s1 : ty == 2 ? s2 : s3;
    const int* dst = ty == 0 ? d0 : ty == 1 ? d1 : ty == 2 ? d2 : d3;
    const ushort* rk = ty == 0 ? rk0 : ty == 1 ? rk1 : ty == 2 ? rk2 : rk3;
    const int* rp = ty == 0 ? r0 : ty == 1 ? r1 : ty == 2 ? r2 : r3;
    ushort* out = ty == 0 ? o0 : ty == 1 ? o1 : ty == 2 ? o2 : o3;
    out[rp[dst[e]] + rk[e]] = (ushort)src[e];
  }
}

// ---------------------------------------------------------------------------
// Combined dual-type gather; halves run concurrently (slots 0-3 half A,
// 4-7 half B). to_csum=1 (last layer): skip the row write, accumulate into
// csum_rep[blockIdx.x & (NREP-1)] — replication kills the r13 457us atomic
// pileup (2.4M atomics on 8 lines -> spread over 64x lines).
__global__ __launch_bounds__(256) void gat_gather_all(
    const int* __restrict__ rp0, const ushort* __restrict__ ss0,
    const int* __restrict__ rp1, const ushort* __restrict__ ss1,
    const int* __restrict__ rp2, const ushort* __restrict__ ss2,
    const int* __restrict__ rp3, const ushort* __restrict__ ss3,
    const float* __restrict__ esE0, const unsigned char* __restrict__ hsE0,
    const float* __restrict__ esE1, const unsigned char* __restrict__ hsE1,
    const float* __restrict__ esP3, const unsigned char* __restrict__ hsP3,
    const float* __restrict__ esP2, const unsigned char* __restrict__ hsP2,
    const float* __restrict__ edEA, const float* __restrict__ edEB,
    const float* __restrict__ edPA, const float* __restrict__ edPB,
    const float* __restrict__ bias, int l, ushort* __restrict__ outxe,
    ushort* __restrict__ outxp, int to_csum, float* __restrict__ csum_rep) {
  const int wid = (blockIdx.x * 256 + threadIdx.x) >> 6;
  const int lane = threadIdx.x & 63;
  const int slot = lane >> 3, sub = lane & 7;
  const int half = slot >> 2;   // 0: type-half A, 1: type-half B
  const int hslot = slot & 3;   // slot within the half
  const bool active = wid < NE_N + NP_N;

  float v0 = 0.f, v1 = 0.f;
  const float *b0 = bias, *b1 = bias;
  ushort* outb = outxe;
  int node = 0;

  if (active) {
    const int *rpA, *rpB;
    const ushort *ssA, *ssB;
    const float *esA, *esB;
    const unsigned char *hsA, *hsB;
    const float *edA, *edB;
    if (wid < NE_N) {  // e-dst: ee (A) + pe (B)
      node = wid;
      rpA = rp0; ssA = ss0; esA = esE0; hsA = hsE0;
      rpB = rp3; ssB = ss3; esB = esP3; hsB = hsP3;
      edA = edEA; edB = edEB;
      b0 = bias + (l * 4 + 0) * DIM; b1 = bias + (l * 4 + 3) * DIM;
      outb = outxe;
    } else {  // p-dst: ep (A) + pp (B)
      node = wid - NE_N;
      rpA = rp1; ssA = ss1; esA = esE1; hsA = hsE1;
      rpB = rp2; ssB = ss2; esB = esP2; hsB = hsP2;
      edA = edPA; edB = edPB;
      b0 = bias + (l * 4 + 1) * DIM; b1 = bias + (l * 4 + 2) * DIM;
      outb = outxp;
    }

    const int* rp = half ? rpB : rpA;
    const ushort* ss = half ? ssB : ssA;
    const float* es = half ? esB : esA;
    const unsigned char* hs = half ? hsB : hsA;
    const float edv = half ? edB[node] : edA[node];
    const int beg = rp[node], end = rp[node + 1];

    float acc[16];
#pragma unroll
    for (int j = 0; j < 16; j++) acc[j] = 0.f;
    float sw = 0.f;

    for (int e = beg + hslot; e < end; e += 4) {
      int s = ss[e];
      float w = exp2f(fmaxf(es[s] + edv, 0.f));
      sw += w;
      uint4 h = *(const uint4*)&hs[(size_t)s * DIM + sub * 16];
      auto p0 = __builtin_amdgcn_cvt_pk_f32_fp8((int)h.x, false);
      auto p1 = __builtin_amdgcn_cvt_pk_f32_fp8((int)h.x, true);
      auto p2 = __builtin_amdgcn_cvt_pk_f32_fp8((int)h.y, false);
      auto p3 = __builtin_amdgcn_cvt_pk_f32_fp8((int)h.y, true);
      auto p4 = __builtin_amdgcn_cvt_pk_f32_fp8((int)h.z, false);
      auto p5 = __builtin_amdgcn_cvt_pk_f32_fp8((int)h.z, true);
      auto p6 = __builtin_amdgcn_cvt_pk_f32_fp8((int)h.w, false);
      auto p7 = __builtin_amdgcn_cvt_pk_f32_fp8((int)h.w, true);
      acc[0] += w * p0[0];  acc[1] += w * p0[1];
      acc[2] += w * p1[0];  acc[3] += w * p1[1];
      acc[4] += w * p2[0];  acc[5] += w * p2[1];
      acc[6] += w * p3[0];  acc[7] += w * p3[1];
      acc[8] += w * p4[0];  acc[9] += w * p4[1];
      acc[10] += w * p5[0]; acc[11] += w * p5[1];
      acc[12] += w * p6[0]; acc[13] += w * p6[1];
      acc[14] += w * p7[0]; acc[15] += w * p7[1];
    }

    // sw over the 4 slots of THIS half (lane bits 3,4)
    sw += __shfl_xor(sw, 8, 64);
    sw += __shfl_xor(sw, 16, 64);
    const float inv = 1.f / fmaxf(sw, 1e-16f);

    float res[16];
#pragma unroll
    for (int j = 0; j < 16; j++) res[j] = acc[j] * inv;

    // combine: slot-partials within half (xor 8,16) + across halves (xor 32)
#pragma unroll
    for (int j = 0; j < 16; j++) {
      res[j] += __shfl_xor(res[j], 8, 64);
      res[j] += __shfl_xor(res[j], 16, 64);
      res[j] += __shfl_xor(res[j], 32, 64);
    }
    v0 = res[slot * 2];
    v1 = res[slot * 2 + 1];
  }

  const int d = sub * 16 + slot * 2;
  if (to_csum) {
    __shared__ float lsum[128];
    if (threadIdx.x < 128) lsum[threadIdx.x] = 0.f;
    __syncthreads();
    if (active) {
      atomicAdd(&lsum[d], v0);
      atomicAdd(&lsum[d + 1], v1);
    }
    __syncthreads();
    if (threadIdx.x < 128) {
      float* rep = csum_rep + (size_t)(blockIdx.x & (NREP - 1)) * DIM;
      unsafeAtomicAdd(&rep[threadIdx.x], lsum[threadIdx.x]);
    }
  } else if (active) {
    float2 bb0 = *(const float2*)&b0[d];
    float2 bb1 = *(const float2*)&b1[d];
    ushort2 o;
    o.x = f2bf(v0 + bb0.x + bb1.x);
    o.y = f2bf(v1 + bb0.y + bb1.y);
    *(ushort2*)&outb[(size_t)node * DIM + d] = o;
  }
}

// ---------------------------------------------------------------------------
// final: reduce NREP csum replicas, add analytic bias term, project.
__global__ __launch_bounds__(128) void final_proj(
    const float* __restrict__ csum_rep, const float* __restrict__ bias,
    const float* __restrict__ lin_W, const float* __restrict__ lin_b,
    float* __restrict__ out) {
  __shared__ float col[DIM];
  int k = threadIdx.x;  // 128 threads, one column each
  float s = 0.f;
  for (int r = 0; r < NREP; r++) s += csum_rep[(size_t)r * DIM + k];
  const float* bE0 = bias + (2 * 4 + 0) * DIM;
  const float* bE1 = bias + (2 * 4 + 3) * DIM;
  const float* bP0 = bias + (2 * 4 + 1) * DIM;
  const float* bP1 = bias + (2 * 4 + 2) * DIM;
  col[k] = s + (float)NE_N * (bE0[k] + bE1[k]) +
           (float)NP_N * (bP0[k] + bP1[k]);
  __syncthreads();
  if (k < 2) {
    float acc = 0.f;
#pragma unroll 8
    for (int j = 0; j < DIM; j++) acc += col[j] * lin_W[j * 2 + k];
    out[k] = acc / (float)(NE_N + NP_N) + lin_b[k];
  }
}

// ---------------------------------------------------------------------------
extern "C" void kernel_launch(void* const* d_in, const int* in_sizes, int n_in,
                              void* d_out, int out_size, void* d_ws,
                              size_t ws_size, hipStream_t stream) {
  const float* x_elem  = (const float*)d_in[0];
  const float* x_proc  = (const float*)d_in[1];
  const float* W_src   = (const float*)d_in[2];
  const float* W_dst   = (const float*)d_in[3];
  const float* att_src = (const float*)d_in[4];
  const float* att_dst = (const float*)d_in[5];
  const float* bias    = (const float*)d_in[6];
  const float* lin_W   = (const float*)d_in[7];
  const float* lin_b   = (const float*)d_in[8];
  const int* esrc[4] = {(const int*)d_in[9],  (const int*)d_in[11],
                        (const int*)d_in[13], (const int*)d_in[15]};
  const int* edst[4] = {(const int*)d_in[10], (const int*)d_in[12],
                        (const int*)d_in[14], (const int*)d_in[16]};

  // ---- workspace carve-up (16B-aligned chunks) ----
  char* p = (char*)d_ws;
  ushort* xe_bf[2]; ushort* xp_bf[2];
  xe_bf[0] = (ushort*)p; p += (size_t)NE_N * DIM * 2;
  xe_bf[1] = (ushort*)p; p += (size_t)NE_N * DIM * 2;
  xp_bf[0] = (ushort*)p; p += (size_t)NP_N * DIM * 2;
  xp_bf[1] = (ushort*)p; p += (size_t)NP_N * DIM * 2;
  unsigned char* hsE0 = (unsigned char*)p; p += (size_t)NE_N * DIM;  // W[l,0]
  unsigned char* hsE1 = (unsigned char*)p; p += (size_t)NE_N * DIM;  // W[l,1]
  unsigned char* hsP3 = (unsigned char*)p; p += (size_t)NP_N * DIM;  // W[l,3]
  unsigned char* hsP2 = (unsigned char*)p; p += (size_t)NP_N * DIM;  // W[l,2]
  ushort* WbT = (ushort*)p; p += (size_t)12 * DIM * DIM * 2;
  float* esE0 = (float*)p; p += (size_t)NE_N * 4;
  float* esE1 = (float*)p; p += (size_t)NE_N * 4;
  float* esP3 = (float*)p; p += (size_t)NP_N * 4;
  float* esP2 = (float*)p; p += (size_t)NP_N * 4;
  float* edEA = (float*)p; p += (size_t)NE_N * 4;
  float* edEB = (float*)p; p += (size_t)NE_N * 4;
  float* edPA = (float*)p; p += (size_t)NP_N * 4;
  float* edPB = (float*)p; p += (size_t)NP_N * 4;
  float* vec = (float*)p; p += 12 * DIM * 4;
  int* parti = (int*)p; p += 4 * 64 * 4;
  // cnt[4] + csum_rep contiguous -> single memset
  int* cnt[4];
  for (int t = 0; t < 4; t++) { cnt[t] = (int*)p; p += (NE_N + 4) * 4; }
  float* csum_rep = (float*)p; p += (size_t)NREP * DIM * 4;
  int* rp[4];
  for (int t = 0; t < 4; t++) { rp[t] = (int*)p; p += (NE_N + 4) * 4; }
  ushort* ssrc[4];
  for (int t = 0; t < 4; t++) { ssrc[t] = (ushort*)p; p += (size_t)E_N * 2; }
  ushort* rank[4];
  for (int t = 0; t < 4; t++) { rank[t] = (ushort*)p; p += (size_t)E_N * 2; }

  // ---- zero cnts + csum replicas in one memset ----
  hipMemsetAsync(cnt[0], 0,
                 4 * (NE_N + 4) * sizeof(int) + NREP * DIM * sizeof(float),
                 stream);

  // ---- fused setup: conv_w | vec | hist+rank ----
  setup_fused<<<SU_CW + SU_V + SU_H, 256, 0, stream>>>(
      W_src, W_dst, att_dst, WbT, vec, edst[0], edst[1], edst[2], edst[3],
      cnt[0], cnt[1], cnt[2], cnt[3], rank[0], rank[1], rank[2], rank[3]);

  // ---- 2-dispatch hierarchical CSR scan ----
  scanA_k<<<dim3(49, 4), 256, 0, stream>>>(cnt[0], cnt[1], cnt[2], cnt[3],
                                           parti);
  scanBC_k<<<dim3(49, 4), 256, 0, stream>>>(cnt[0], cnt[1], cnt[2], cnt[3],
                                            rp[0], rp[1], rp[2], rp[3], parti);

  // ---- atomic-free fill + layer-0 gemm (fp32 input) fused ----
  fill_gemm0_k<<<GEMM_BLK + 3128, 256, 0, stream>>>(
      x_elem, x_proc, WbT, att_src, vec, hsE0, hsE1, hsP3, hsP2, esE0, esE1,
      esP3, esP2, edEA, edEB, edPA, edPB, esrc[0], esrc[1], esrc[2], esrc[3],
      edst[0], edst[1], edst[2], edst[3], rank[0], rank[1], rank[2], rank[3],
      rp[0], rp[1], rp[2], rp[3], ssrc[0], ssrc[1], ssrc[2], ssrc[3]);

  // ---- layers ----
  int c = 0;
  for (int l = 0; l < 3; l++) {
    if (l > 0) {
      gemm_k<<<GEMM_BLK, 256, 0, stream>>>(
          xe_bf[c], xp_bf[c], WbT, att_src, vec, l, hsE0, hsE1, hsP3, hsP2,
          esE0, esE1, esP3, esP2, edEA, edEB, edPA, edPB);
    }
    int to_csum = (l == 2) ? 1 : 0;
    gat_gather_all<<<(NE_N + NP_N) / 4, 256, 0, stream>>>(
        rp[0], ssrc[0], rp[1], ssrc[1], rp[2], ssrc[2], rp[3], ssrc[3], esE0,
        hsE0, esE1, hsE1, esP3, hsP3, esP2, hsP2, edEA, edEB, edPA, edPB,
        bias, l, xe_bf[1 - c], xp_bf[1 - c], to_csum, csum_rep);
    c = 1 - c;
  }

  final_proj<<<1, 128, 0, stream>>>(csum_rep, bias, lin_W, lin_b,
                                    (float*)d_out);
}

// Round 15
// 469.653 us; speedup vs baseline: 1.8655x; 1.0817x over previous
//
#include <hip/hip_runtime.h>

#define NE_N 50000
#define NP_N 25000
#define E_N 200000
#define DIM 128
#define LOG2E 1.4426950408889634f
#define NREP 1024  // csum replicas: 2.4M atomics / (1024*128 addrs) = 18/addr

typedef __attribute__((ext_vector_type(8))) short short8;
typedef __attribute__((ext_vector_type(4))) float f32x4;

static __device__ __forceinline__ ushort f2bf(float f) {
  unsigned x = __float_as_uint(f);
  return (ushort)((x + 0x7fffu + ((x >> 16) & 1u)) >> 16);  // RNE
}
static __device__ __forceinline__ float bf2f(ushort u) {
  return __uint_as_float(((unsigned)u) << 16);
}

// ---------------------------------------------------------------------------
// Fused setup: conv_w (12 blk) | vec (6 blk) | hist+rank (3128 blk).
#define SU_CW 12
#define SU_V 6
#define SU_H 3128
__global__ __launch_bounds__(256) void setup_fused(
    const float* __restrict__ W_src, const float* __restrict__ W_dst,
    const float* __restrict__ att_dst, ushort* __restrict__ WbT,
    float* __restrict__ vec, const int* __restrict__ d0,
    const int* __restrict__ d1, const int* __restrict__ d2,
    const int* __restrict__ d3, int* __restrict__ c0, int* __restrict__ c1,
    int* __restrict__ c2, int* __restrict__ c3, ushort* __restrict__ rk0,
    ushort* __restrict__ rk1, ushort* __restrict__ rk2,
    ushort* __restrict__ rk3) {
  int blk = blockIdx.x;
  int tid = threadIdx.x;
  if (blk < SU_CW) {
    const float* src = W_src + (size_t)blk * DIM * DIM;
    ushort* dst = WbT + (size_t)blk * DIM * DIM;
    for (int i = tid; i < DIM * DIM; i += 256) {
      int k = i >> 7, n = i & 127;
      dst[n * DIM + k] = f2bf(src[i]);
    }
  } else if (blk < SU_CW + SU_V) {
    int b = blk - SU_CW;
    int lt = b * 2 + (tid >> 7);
    int i = tid & 127;
    const float* Wd = W_dst + (size_t)lt * DIM * DIM;
    const float* ad = att_dst + lt * DIM;
    float s = 0.f;
#pragma unroll 8
    for (int j = 0; j < DIM; j++) s += Wd[i * DIM + j] * ad[j];
    vec[lt * DIM + i] = s;
  } else {
    int b = blk - SU_CW - SU_V;
    int ty = b / 782;
    int e = (b % 782) * 256 + tid;
    if (e >= E_N) return;
    const int* dst = ty == 0 ? d0 : ty == 1 ? d1 : ty == 2 ? d2 : d3;
    int* cnt = ty == 0 ? c0 : ty == 1 ? c1 : ty == 2 ? c2 : c3;
    ushort* rk = ty == 0 ? rk0 : ty == 1 ? rk1 : ty == 2 ? rk2 : rk3;
    rk[e] = (ushort)atomicAdd(&cnt[dst[e]], 1);
  }
}

// ---------------------------------------------------------------------------
// CSR scan, 2 dispatches: scanA (block sums) + scanBC (inline partial prefix
// + writeback). r9's 1-dispatch scan: 92us. r11 coop mega: 1519us.
__global__ __launch_bounds__(256) void scanA_k(
    const int* __restrict__ c0, const int* __restrict__ c1,
    const int* __restrict__ c2, const int* __restrict__ c3,
    int* __restrict__ part) {
  int ty = blockIdx.y;
  const int* cnt = ty == 0 ? c0 : ty == 1 ? c1 : ty == 2 ? c2 : c3;
  int n = (ty == 0 || ty == 3) ? NE_N : NP_N;
  int nblk = (n + 1023) >> 10;
  if ((int)blockIdx.x >= nblk) return;
  int base = blockIdx.x * 1024 + threadIdx.x * 4;
  int s = 0;
#pragma unroll
  for (int j = 0; j < 4; j++) s += (base + j < n) ? cnt[base + j] : 0;
  int lane = threadIdx.x & 63, wid = threadIdx.x >> 6;
#pragma unroll
  for (int off = 32; off > 0; off >>= 1) s += __shfl_xor(s, off, 64);
  __shared__ int ws4[4];
  if (lane == 0) ws4[wid] = s;
  __syncthreads();
  if (threadIdx.x == 0)
    part[ty * 64 + blockIdx.x] = ws4[0] + ws4[1] + ws4[2] + ws4[3];
}

__global__ __launch_bounds__(256) void scanBC_k(
    const int* __restrict__ c0, const int* __restrict__ c1,
    const int* __restrict__ c2, const int* __restrict__ c3,
    int* __restrict__ r0, int* __restrict__ r1, int* __restrict__ r2,
    int* __restrict__ r3, const int* __restrict__ part) {
  int ty = blockIdx.y;
  int bx = blockIdx.x;
  const int* cnt = ty == 0 ? c0 : ty == 1 ? c1 : ty == 2 ? c2 : c3;
  int* rp = ty == 0 ? r0 : ty == 1 ? r1 : ty == 2 ? r2 : r3;
  int n = (ty == 0 || ty == 3) ? NE_N : NP_N;
  int nblk = (n + 1023) >> 10;
  if (bx >= nblk) return;

  __shared__ int s_excl;
  if (threadIdx.x < 64) {
    int pl = threadIdx.x;
    int v = (pl < nblk) ? part[ty * 64 + pl] : 0;
    int sc = v;
#pragma unroll
    for (int off = 1; off < 64; off <<= 1) {
      int t = __shfl_up(sc, off, 64);
      if (pl >= off) sc += t;
    }
    if (pl == bx) s_excl = sc - v;
  }
  if (bx == 0 && threadIdx.x == 0) rp[n] = E_N;  // total is always E_N
  __syncthreads();

  int base = bx * 1024 + threadIdx.x * 4;
  int v[4];
#pragma unroll
  for (int j = 0; j < 4; j++) v[j] = (base + j < n) ? cnt[base + j] : 0;
  int s = v[0] + v[1] + v[2] + v[3];
  int lane = threadIdx.x & 63, wid = threadIdx.x >> 6;
  int sc = s;
#pragma unroll
  for (int off = 1; off < 64; off <<= 1) {
    int t = __shfl_up(sc, off, 64);
    if (lane >= off) sc += t;
  }
  __shared__ int ws4[4];
  if (lane == 63) ws4[wid] = sc;
  __syncthreads();
  int wbase = 0;
  for (int w = 0; w < wid; w++) wbase += ws4[w];
  int p = s_excl + wbase + sc - s;
#pragma unroll
  for (int j = 0; j < 4; j++) {
    if (base + j < n) rp[base + j] = p;
    p += v[j];
  }
}

// ---------------------------------------------------------------------------
// GEMM body: operand-swapped MFMA; es (scaled LOG2E) + ed for both dst
// halves. FP32 template: layer 0 reads raw fp32 features (no conv pass).
#define EBLK ((NE_N + 63) / 64)
#define PBLK ((NP_N + 63) / 64)
#define GEMM_BLK (EBLK + PBLK)
template <bool FP32>
static __device__ __forceinline__ void gemm_body(
    int blk, const void* __restrict__ xev, const void* __restrict__ xpv,
    const ushort* __restrict__ WbT, const float* __restrict__ att,
    const float* __restrict__ vec, int l, unsigned char* __restrict__ hsE0,
    unsigned char* __restrict__ hsE1, unsigned char* __restrict__ hsP3,
    unsigned char* __restrict__ hsP2, float* __restrict__ esE0,
    float* __restrict__ esE1, float* __restrict__ esP3,
    float* __restrict__ esP2, float* __restrict__ edEA,
    float* __restrict__ edEB, float* __restrict__ edPA,
    float* __restrict__ edPB) {
  const void* xb;
  const ushort *W0T, *W1T;
  const float *a0, *a1, *dv0, *dv1;
  unsigned char *hs0, *hs1;
  float *es0, *es1, *edA, *edB;
  int N;
  if (blk < EBLK) {
    xb = xev; N = NE_N;
    W0T = WbT + (size_t)(l * 4 + 0) * DIM * DIM;
    W1T = WbT + (size_t)(l * 4 + 1) * DIM * DIM;
    a0 = att + (l * 4 + 0) * DIM; a1 = att + (l * 4 + 1) * DIM;
    dv0 = vec + (l * 4 + 0) * DIM; dv1 = vec + (l * 4 + 3) * DIM;
    hs0 = hsE0; hs1 = hsE1; es0 = esE0; es1 = esE1;
    edA = edEA; edB = edEB;
  } else {
    blk -= EBLK; xb = xpv; N = NP_N;
    W0T = WbT + (size_t)(l * 4 + 3) * DIM * DIM;
    W1T = WbT + (size_t)(l * 4 + 2) * DIM * DIM;
    a0 = att + (l * 4 + 3) * DIM; a1 = att + (l * 4 + 2) * DIM;
    dv0 = vec + (l * 4 + 1) * DIM; dv1 = vec + (l * 4 + 2) * DIM;
    hs0 = hsP3; hs1 = hsP2; es0 = esP3; es1 = esP2;
    edA = edPA; edB = edPB;
  }

  const int wave = threadIdx.x >> 6;
  const int lane = threadIdx.x & 63;
  const int m = lane & 15, quad = lane >> 4;
  const int row0 = blk * 64 + wave * 16;
  if (row0 >= N) return;
  int rowA = row0 + m;
  if (rowA >= N) rowA = N - 1;  // clamp loads; stores guarded

  f32x4 acc0[8], acc1[8];
#pragma unroll
  for (int f = 0; f < 8; f++) {
    acc0[f] = (f32x4){0.f, 0.f, 0.f, 0.f};
    acc1[f] = (f32x4){0.f, 0.f, 0.f, 0.f};
  }

  float edp0 = 0.f, edp1 = 0.f;
  const float* xf32 = (const float*)xb + (size_t)rowA * DIM + quad * 8;
  const ushort* xb16 = (const ushort*)xb + (size_t)rowA * DIM + quad * 8;
#pragma unroll
  for (int k0 = 0; k0 < 4; k0++) {
    short8 xv;
    float xf[8];
    if (FP32) {
      float4 f0 = *(const float4*)(xf32 + k0 * 32);
      float4 f1 = *(const float4*)(xf32 + k0 * 32 + 4);
      xf[0] = f0.x; xf[1] = f0.y; xf[2] = f0.z; xf[3] = f0.w;
      xf[4] = f1.x; xf[5] = f1.y; xf[6] = f1.z; xf[7] = f1.w;
#pragma unroll
      for (int j = 0; j < 8; j++) xv[j] = (short)f2bf(xf[j]);
    } else {
      xv = *(const short8*)(xb16 + k0 * 32);
#pragma unroll
      for (int j = 0; j < 8; j++) xf[j] = bf2f((ushort)xv[j]);
    }
    // ed partials
    {
      int off = k0 * 32 + quad * 8;
      float4 vA0 = *(const float4*)&dv0[off];
      float4 vA1 = *(const float4*)&dv0[off + 4];
      float4 vB0 = *(const float4*)&dv1[off];
      float4 vB1 = *(const float4*)&dv1[off + 4];
      edp0 += xf[0] * vA0.x + xf[1] * vA0.y + xf[2] * vA0.z + xf[3] * vA0.w +
              xf[4] * vA1.x + xf[5] * vA1.y + xf[6] * vA1.z + xf[7] * vA1.w;
      edp1 += xf[0] * vB0.x + xf[1] * vB0.y + xf[2] * vB0.z + xf[3] * vB0.w +
              xf[4] * vB1.x + xf[5] * vB1.y + xf[6] * vB1.z + xf[7] * vB1.w;
    }
#pragma unroll
    for (int f = 0; f < 8; f++) {
      size_t boff = (size_t)(f * 16 + m) * DIM + k0 * 32 + quad * 8;
      short8 w0 = *(const short8*)(W0T + boff);
      acc0[f] = __builtin_amdgcn_mfma_f32_16x16x32_bf16(w0, xv, acc0[f], 0, 0, 0);
      short8 w1 = *(const short8*)(W1T + boff);
      acc1[f] = __builtin_amdgcn_mfma_f32_16x16x32_bf16(w1, xv, acc1[f], 0, 0, 0);
    }
  }

  const int row = row0 + m;
  edp0 += __shfl_xor(edp0, 16, 64);
  edp0 += __shfl_xor(edp0, 32, 64);
  edp1 += __shfl_xor(edp1, 16, 64);
  edp1 += __shfl_xor(edp1, 32, 64);
  if (quad == 0 && row < N) {
    edA[row] = edp0 * LOG2E;
    edB[row] = edp1 * LOG2E;
  }

#pragma unroll
  for (int set = 0; set < 2; set++) {
    f32x4* acc = set ? acc1 : acc0;
    const float* as = set ? a1 : a0;
    float* es = set ? es1 : es0;
    unsigned char* hs = set ? hs1 : hs0;

    float esum = 0.f;
#pragma unroll
    for (int f = 0; f < 8; f++) {
      float4 av = *(const float4*)&as[f * 16 + quad * 4];
      esum += acc[f][0] * av.x + acc[f][1] * av.y + acc[f][2] * av.z +
              acc[f][3] * av.w;
    }
    esum += __shfl_xor(esum, 16, 64);
    esum += __shfl_xor(esum, 32, 64);
    if (quad == 0 && row < N) es[row] = esum * LOG2E;

    if (row < N) {
#pragma unroll
      for (int f = 0; f < 8; f++) {
        int w = __builtin_amdgcn_cvt_pk_fp8_f32(acc[f][0], acc[f][1], 0, false);
        w = __builtin_amdgcn_cvt_pk_fp8_f32(acc[f][2], acc[f][3], w, true);
        *(unsigned*)&hs[(size_t)row * DIM + f * 16 + quad * 4] = (unsigned)w;
      }
    }
  }
}

// standalone gemm (layers 1,2 — bf16 input)
__global__ __launch_bounds__(256) void gemm_k(
    const ushort* __restrict__ xe, const ushort* __restrict__ xp,
    const ushort* __restrict__ WbT, const float* __restrict__ att,
    const float* __restrict__ vec, int l, unsigned char* __restrict__ hsE0,
    unsigned char* __restrict__ hsE1, unsigned char* __restrict__ hsP3,
    unsigned char* __restrict__ hsP2, float* __restrict__ esE0,
    float* __restrict__ esE1, float* __restrict__ esP3,
    float* __restrict__ esP2, float* __restrict__ edEA,
    float* __restrict__ edEB, float* __restrict__ edPA,
    float* __restrict__ edPB) {
  gemm_body<false>(blockIdx.x, xe, xp, WbT, att, vec, l, hsE0, hsE1, hsP3,
                   hsP2, esE0, esE1, esP3, esP2, edEA, edEB, edPA, edPB);
}

// fused atomic-free CSR-fill + layer-0 gemm (fp32 input)
__global__ __launch_bounds__(256) void fill_gemm0_k(
    const float* __restrict__ xe, const float* __restrict__ xp,
    const ushort* __restrict__ WbT, const float* __restrict__ att,
    const float* __restrict__ vec, unsigned char* __restrict__ hsE0,
    unsigned char* __restrict__ hsE1, unsigned char* __restrict__ hsP3,
    unsigned char* __restrict__ hsP2, float* __restrict__ esE0,
    float* __restrict__ esE1, float* __restrict__ esP3,
    float* __restrict__ esP2, float* __restrict__ edEA,
    float* __restrict__ edEB, float* __restrict__ edPA,
    float* __restrict__ edPB, const int* __restrict__ s0,
    const int* __restrict__ s1, const int* __restrict__ s2,
    const int* __restrict__ s3, const int* __restrict__ d0,
    const int* __restrict__ d1, const int* __restrict__ d2,
    const int* __restrict__ d3, const ushort* __restrict__ rk0,
    const ushort* __restrict__ rk1, const ushort* __restrict__ rk2,
    const ushort* __restrict__ rk3, const int* __restrict__ r0,
    const int* __restrict__ r1, const int* __restrict__ r2,
    const int* __restrict__ r3, ushort* __restrict__ o0,
    ushort* __restrict__ o1, ushort* __restrict__ o2,
    ushort* __restrict__ o3) {
  int blk = blockIdx.x;
  if (blk < GEMM_BLK) {
    gemm_body<true>(blk, xe, xp, WbT, att, vec, 0, hsE0, hsE1, hsP3, hsP2,
                    esE0, esE1, esP3, esP2, edEA, edEB, edPA, edPB);
  } else {
    int b = blk - GEMM_BLK;
    int ty = b / 782;
    int e = (b % 782) * 256 + threadIdx.x;
    if (e >= E_N) return;
    const int* src = ty == 0 ? s0 : ty == 1 ? s1 : ty == 2 ? s2 : s3;
    const int* dst = ty == 0 ? d0 : ty == 1 ? d1 : ty == 2 ? d2 : d3;
    const ushort* rk = ty == 0 ? rk0 : ty == 1 ? rk1 : ty == 2 ? rk2 : rk3;
    const int* rp = ty == 0 ? r0 : ty == 1 ? r1 : ty == 2 ? r2 : r3;
    ushort* out = ty == 0 ? o0 : ty == 1 ? o1 : ty == 2 ? o2 : o3;
    out[rp[dst[e]] + rk[e]] = (ushort)src[e];
  }
}

// ---------------------------------------------------------------------------
// Combined dual-type gather; halves run concurrently (slots 0-3 half A,
// 4-7 half B). to_csum=1 (last layer): skip the row write; per-wave plain
// LDS stores (d covers all 128 cols exactly once per wave), cross-wave sum,
// then ONE uncontended global atomic per column into replica blk&(NREP-1).
__global__ __launch_bounds__(256) void gat_gather_all(
    const int* __restrict__ rp0, const ushort* __restrict__ ss0,
    const int* __restrict__ rp1, const ushort* __restrict__ ss1,
    const int* __restrict__ rp2, const ushort* __restrict__ ss2,
    const int* __restrict__ rp3, const ushort* __restrict__ ss3,
    const float* __restrict__ esE0, const unsigned char* __restrict__ hsE0,
    const float* __restrict__ esE1, const unsigned char* __restrict__ hsE1,
    const float* __restrict__ esP3, const unsigned char* __restrict__ hsP3,
    const float* __restrict__ esP2, const unsigned char* __restrict__ hsP2,
    const float* __restrict__ edEA, const float* __restrict__ edEB,
    const float* __restrict__ edPA, const float* __restrict__ edPB,
    const float* __restrict__ bias, int l, ushort* __restrict__ outxe,
    ushort* __restrict__ outxp, int to_csum, float* __restrict__ csum_rep) {
  const int wid = (blockIdx.x * 256 + threadIdx.x) >> 6;
  const int lane = threadIdx.x & 63;
  const int slot = lane >> 3, sub = lane & 7;
  const int half = slot >> 2;   // 0: type-half A, 1: type-half B
  const int hslot = slot & 3;   // slot within the half
  const bool active = wid < NE_N + NP_N;

  float v0 = 0.f, v1 = 0.f;
  const float *b0 = bias, *b1 = bias;
  ushort* outb = outxe;
  int node = 0;

  if (active) {
    const int *rpA, *rpB;
    const ushort *ssA, *ssB;
    const float *esA, *esB;
    const unsigned char *hsA, *hsB;
    const float *edA, *edB;
    if (wid < NE_N) {  // e-dst: ee (A) + pe (B)
      node = wid;
      rpA = rp0; ssA = ss0; esA = esE0; hsA = hsE0;
      rpB = rp3; ssB = ss3; esB = esP3; hsB = hsP3;
      edA = edEA; edB = edEB;
      b0 = bias + (l * 4 + 0) * DIM; b1 = bias + (l * 4 + 3) * DIM;
      outb = outxe;
    } else {  // p-dst: ep (A) + pp (B)
      node = wid - NE_N;
      rpA = rp1; ssA = ss1; esA = esE1; hsA = hsE1;
      rpB = rp2; ssB = ss2; esB = esP2; hsB = hsP2;
      edA = edPA; edB = edPB;
      b0 = bias + (l * 4 + 1) * DIM; b1 = bias + (l * 4 + 2) * DIM;
      outb = outxp;
    }

    const int* rp = half ? rpB : rpA;
    const ushort* ss = half ? ssB : ssA;
    const float* es = half ? esB : esA;
    const unsigned char* hs = half ? hsB : hsA;
    const float edv = half ? edB[node] : edA[node];
    const int beg = rp[node], end = rp[node + 1];

    float acc[16];
#pragma unroll
    for (int j = 0; j < 16; j++) acc[j] = 0.f;
    float sw = 0.f;

    for (int e = beg + hslot; e < end; e += 4) {
      int s = ss[e];
      float w = exp2f(fmaxf(es[s] + edv, 0.f));
      sw += w;
      uint4 h = *(const uint4*)&hs[(size_t)s * DIM + sub * 16];
      auto p0 = __builtin_amdgcn_cvt_pk_f32_fp8((int)h.x, false);
      auto p1 = __builtin_amdgcn_cvt_pk_f32_fp8((int)h.x, true);
      auto p2 = __builtin_amdgcn_cvt_pk_f32_fp8((int)h.y, false);
      auto p3 = __builtin_amdgcn_cvt_pk_f32_fp8((int)h.y, true);
      auto p4 = __builtin_amdgcn_cvt_pk_f32_fp8((int)h.z, false);
      auto p5 = __builtin_amdgcn_cvt_pk_f32_fp8((int)h.z, true);
      auto p6 = __builtin_amdgcn_cvt_pk_f32_fp8((int)h.w, false);
      auto p7 = __builtin_amdgcn_cvt_pk_f32_fp8((int)h.w, true);
      acc[0] += w * p0[0];  acc[1] += w * p0[1];
      acc[2] += w * p1[0];  acc[3] += w * p1[1];
      acc[4] += w * p2[0];  acc[5] += w * p2[1];
      acc[6] += w * p3[0];  acc[7] += w * p3[1];
      acc[8] += w * p4[0];  acc[9] += w * p4[1];
      acc[10] += w * p5[0]; acc[11] += w * p5[1];
      acc[12] += w * p6[0]; acc[13] += w * p6[1];
      acc[14] += w * p7[0]; acc[15] += w * p7[1];
    }

    // sw over the 4 slots of THIS half (lane bits 3,4)
    sw += __shfl_xor(sw, 8, 64);
    sw += __shfl_xor(sw, 16, 64);
    const float inv = 1.f / fmaxf(sw, 1e-16f);

    float res[16];
#pragma unroll
    for (int j = 0; j < 16; j++) res[j] = acc[j] * inv;

    // combine: slot-partials within half (xor 8,16) + across halves (xor 32)
#pragma unroll
    for (int j = 0; j < 16; j++) {
      res[j] += __shfl_xor(res[j], 8, 64);
      res[j] += __shfl_xor(res[j], 16, 64);
      res[j] += __shfl_xor(res[j], 32, 64);
    }
    v0 = res[slot * 2];
    v1 = res[slot * 2 + 1];
  }

  const int d = sub * 16 + slot * 2;
  if (to_csum) {
    // per-wave d covers all 128 cols exactly once -> plain LDS stores
    __shared__ float lsum[4][DIM];
    const int wv = threadIdx.x >> 6;
    lsum[wv][d] = v0;
    lsum[wv][d + 1] = v1;
    __syncthreads();
    if (threadIdx.x < DIM) {
      float s = lsum[0][threadIdx.x] + lsum[1][threadIdx.x] +
                lsum[2][threadIdx.x] + lsum[3][threadIdx.x];
      float* rep = csum_rep + (size_t)(blockIdx.x & (NREP - 1)) * DIM;
      unsafeAtomicAdd(&rep[threadIdx.x], s);
    }
  } else if (active) {
    float2 bb0 = *(const float2*)&b0[d];
    float2 bb1 = *(const float2*)&b1[d];
    ushort2 o;
    o.x = f2bf(v0 + bb0.x + bb1.x);
    o.y = f2bf(v1 + bb0.y + bb1.y);
    *(ushort2*)&outb[(size_t)node * DIM + d] = o;
  }
}

// ---------------------------------------------------------------------------
// final: reduce NREP csum replicas (512 thr: 4-way replica split, coalesced),
// add analytic bias term, project.
__global__ __launch_bounds__(512) void final_proj(
    const float* __restrict__ csum_rep, const float* __restrict__ bias,
    const float* __restrict__ lin_W, const float* __restrict__ lin_b,
    float* __restrict__ out) {
  __shared__ float parts[4][DIM];
  __shared__ float col[DIM];
  const int k = threadIdx.x & 127;   // column
  const int pt = threadIdx.x >> 7;   // replica partition 0..3
  float s = 0.f;
#pragma unroll 8
  for (int r = pt * (NREP / 4); r < (pt + 1) * (NREP / 4); r++)
    s += csum_rep[(size_t)r * DIM + k];
  parts[pt][k] = s;
  __syncthreads();
  if (threadIdx.x < DIM) {
    const float* bE0 = bias + (2 * 4 + 0) * DIM;
    const float* bE1 = bias + (2 * 4 + 3) * DIM;
    const float* bP0 = bias + (2 * 4 + 1) * DIM;
    const float* bP1 = bias + (2 * 4 + 2) * DIM;
    col[k] = parts[0][k] + parts[1][k] + parts[2][k] + parts[3][k] +
             (float)NE_N * (bE0[k] + bE1[k]) +
             (float)NP_N * (bP0[k] + bP1[k]);
  }
  __syncthreads();
  if (threadIdx.x < 2) {
    float acc = 0.f;
#pragma unroll 8
    for (int j = 0; j < DIM; j++) acc += col[j] * lin_W[j * 2 + threadIdx.x];
    out[threadIdx.x] = acc / (float)(NE_N + NP_N) + lin_b[threadIdx.x];
  }
}

// ---------------------------------------------------------------------------
extern "C" void kernel_launch(void* const* d_in, const int* in_sizes, int n_in,
                              void* d_out, int out_size, void* d_ws,
                              size_t ws_size, hipStream_t stream) {
  const float* x_elem  = (const float*)d_in[0];
  const float* x_proc  = (const float*)d_in[1];
  const float* W_src   = (const float*)d_in[2];
  const float* W_dst   = (const float*)d_in[3];
  const float* att_src = (const float*)d_in[4];
  const float* att_dst = (const float*)d_in[5];
  const float* bias    = (const float*)d_in[6];
  const float* lin_W   = (const float*)d_in[7];
  const float* lin_b   = (const float*)d_in[8];
  const int* esrc[4] = {(const int*)d_in[9],  (const int*)d_in[11],
                        (const int*)d_in[13], (const int*)d_in[15]};
  const int* edst[4] = {(const int*)d_in[10], (const int*)d_in[12],
                        (const int*)d_in[14], (const int*)d_in[16]};

  // ---- workspace carve-up (16B-aligned chunks) ----
  char* p = (char*)d_ws;
  ushort* xe_bf[2]; ushort* xp_bf[2];
  xe_bf[0] = (ushort*)p; p += (size_t)NE_N * DIM * 2;
  xe_bf[1] = (ushort*)p; p += (size_t)NE_N * DIM * 2;
  xp_bf[0] = (ushort*)p; p += (size_t)NP_N * DIM * 2;
  xp_bf[1] = (ushort*)p; p += (size_t)NP_N * DIM * 2;
  unsigned char* hsE0 = (unsigned char*)p; p += (size_t)NE_N * DIM;  // W[l,0]
  unsigned char* hsE1 = (unsigned char*)p; p += (size_t)NE_N * DIM;  // W[l,1]
  unsigned char* hsP3 = (unsigned char*)p; p += (size_t)NP_N * DIM;  // W[l,3]
  unsigned char* hsP2 = (unsigned char*)p; p += (size_t)NP_N * DIM;  // W[l,2]
  ushort* WbT = (ushort*)p; p += (size_t)12 * DIM * DIM * 2;
  float* esE0 = (float*)p; p += (size_t)NE_N * 4;
  float* esE1 = (float*)p; p += (size_t)NE_N * 4;
  float* esP3 = (float*)p; p += (size_t)NP_N * 4;
  float* esP2 = (float*)p; p += (size_t)NP_N * 4;
  float* edEA = (float*)p; p += (size_t)NE_N * 4;
  float* edEB = (float*)p; p += (size_t)NE_N * 4;
  float* edPA = (float*)p; p += (size_t)NP_N * 4;
  float* edPB = (float*)p; p += (size_t)NP_N * 4;
  float* vec = (float*)p; p += 12 * DIM * 4;
  int* parti = (int*)p; p += 4 * 64 * 4;
  // cnt[4] + csum_rep contiguous -> single memset
  int* cnt[4];
  for (int t = 0; t < 4; t++) { cnt[t] = (int*)p; p += (NE_N + 4) * 4; }
  float* csum_rep = (float*)p; p += (size_t)NREP * DIM * 4;
  int* rp[4];
  for (int t = 0; t < 4; t++) { rp[t] = (int*)p; p += (NE_N + 4) * 4; }
  ushort* ssrc[4];
  for (int t = 0; t < 4; t++) { ssrc[t] = (ushort*)p; p += (size_t)E_N * 2; }
  ushort* rank[4];
  for (int t = 0; t < 4; t++) { rank[t] = (ushort*)p; p += (size_t)E_N * 2; }

  // ---- zero cnts + csum replicas in one memset ----
  hipMemsetAsync(cnt[0], 0,
                 4 * (NE_N + 4) * sizeof(int) + (size_t)NREP * DIM * sizeof(float),
                 stream);

  // ---- fused setup: conv_w | vec | hist+rank ----
  setup_fused<<<SU_CW + SU_V + SU_H, 256, 0, stream>>>(
      W_src, W_dst, att_dst, WbT, vec, edst[0], edst[1], edst[2], edst[3],
      cnt[0], cnt[1], cnt[2], cnt[3], rank[0], rank[1], rank[2], rank[3]);

  // ---- 2-dispatch hierarchical CSR scan ----
  scanA_k<<<dim3(49, 4), 256, 0, stream>>>(cnt[0], cnt[1], cnt[2], cnt[3],
                                           parti);
  scanBC_k<<<dim3(49, 4), 256, 0, stream>>>(cnt[0], cnt[1], cnt[2], cnt[3],
                                            rp[0], rp[1], rp[2], rp[3], parti);

  // ---- atomic-free fill + layer-0 gemm (fp32 input) fused ----
  fill_gemm0_k<<<GEMM_BLK + 3128, 256, 0, stream>>>(
      x_elem, x_proc, WbT, att_src, vec, hsE0, hsE1, hsP3, hsP2, esE0, esE1,
      esP3, esP2, edEA, edEB, edPA, edPB, esrc[0], esrc[1], esrc[2], esrc[3],
      edst[0], edst[1], edst[2], edst[3], rank[0], rank[1], rank[2], rank[3],
      rp[0], rp[1], rp[2], rp[3], ssrc[0], ssrc[1], ssrc[2], ssrc[3]);

  // ---- layers ----
  int c = 0;
  for (int l = 0; l < 3; l++) {
    if (l > 0) {
      gemm_k<<<GEMM_BLK, 256, 0, stream>>>(
          xe_bf[c], xp_bf[c], WbT, att_src, vec, l, hsE0, hsE1, hsP3, hsP2,
          esE0, esE1, esP3, esP2, edEA, edEB, edPA, edPB);
    }
    int to_csum = (l == 2) ? 1 : 0;
    gat_gather_all<<<(NE_N + NP_N) / 4, 256, 0, stream>>>(
        rp[0], ssrc[0], rp[1], ssrc[1], rp[2], ssrc[2], rp[3], ssrc[3], esE0,
        hsE0, esE1, hsE1, esP3, hsP3, esP2, hsP2, edEA, edEB, edPA, edPB,
        bias, l, xe_bf[1 - c], xp_bf[1 - c], to_csum, csum_rep);
    c = 1 - c;
  }

  final_proj<<<1, 512, 0, stream>>>(csum_rep, bias, lin_W, lin_b,
                                    (float*)d_out);
}